// Round 1
// baseline (518.922 us; speedup 1.0000x reference)
//
#include <hip/hip_runtime.h>

#define SQ 4096
#define SKV 1024
#define BATCH 4
#define NH 8
#define DH 64
#define QD 1024
#define CD 768
#define INNER 512

typedef _Float16 half8 __attribute__((ext_vector_type(8)));
typedef _Float16 half4v __attribute__((ext_vector_type(4)));
typedef float floatx4 __attribute__((ext_vector_type(4)));

#define MFMA16(a, b, c) __builtin_amdgcn_mfma_f32_16x16x32_f16(a, b, c, 0, 0, 0)

// ---------------------------------------------------------------- fp32 -> fp16
__global__ __launch_bounds__(256) void cvt_f32_f16(const float* __restrict__ src,
                                                   _Float16* __restrict__ dst, int n4) {
  int i = blockIdx.x * 256 + threadIdx.x;
  if (i >= n4) return;
  float4 v = ((const float4*)src)[i];
  half4v o;
  o[0] = (_Float16)v.x; o[1] = (_Float16)v.y; o[2] = (_Float16)v.z; o[3] = (_Float16)v.w;
  *(half4v*)(dst + (size_t)i * 4) = o;
}

// ---------------------------------------------------------------- tiled GEMM
// C[M,N] = A[M,K] @ B[K,N].  A row-major (fp32 if AF32 else fp16), B fp16 row-major.
// MODE 0: fp16 out row-major. MODE 1: fp16 out scattered to vT[b][h][d][kv].
// MODE 2: fp32 out + bias.
// Block: 256 thr (4 waves). Tile 64x64, BK=32. Wave w owns rows [16w,16w+16).
template <int MODE, int AF32>
__global__ __launch_bounds__(256) void gemm16(const void* __restrict__ Aany,
                                              const _Float16* __restrict__ B,
                                              void* __restrict__ Cout,
                                              const float* __restrict__ bias,
                                              int M, int N, int K) {
  __shared__ _Float16 As[64 * 32];
  __shared__ _Float16 Bs[64 * 32];  // transposed: [n][k]
  const int tid = threadIdx.x;
  const int wave = tid >> 6, lane = tid & 63;
  const int quad = lane >> 4, l16 = lane & 15;
  const int m0 = blockIdx.x * 64, n0 = blockIdx.y * 64;

  floatx4 acc[4] = {{0.f, 0.f, 0.f, 0.f}, {0.f, 0.f, 0.f, 0.f},
                    {0.f, 0.f, 0.f, 0.f}, {0.f, 0.f, 0.f, 0.f}};

  const int arow = tid >> 2;        // 0..63
  const int acol = (tid & 3) * 8;   // 0,8,16,24
  const int bn = tid & 63;          // 0..63 (n)
  const int bk = (tid >> 6) * 8;    // 0,8,16,24 (k)
  const int bcol = n0 + bn;

  const size_t aoff = (size_t)(m0 + arow) * K + acol;

  for (int k0 = 0; k0 < K; k0 += 32) {
    // ---- fetch A slice (16B of fp16 worth) ----
    half8 av;
    if (AF32) {
      const float* a32 = (const float*)Aany;
      float4 u = *(const float4*)(a32 + aoff + k0);
      float4 w = *(const float4*)(a32 + aoff + k0 + 4);
      av[0] = (_Float16)u.x; av[1] = (_Float16)u.y; av[2] = (_Float16)u.z; av[3] = (_Float16)u.w;
      av[4] = (_Float16)w.x; av[5] = (_Float16)w.y; av[6] = (_Float16)w.z; av[7] = (_Float16)w.w;
    } else {
      av = *(const half8*)((const _Float16*)Aany + aoff + k0);
    }
    // ---- fetch B slice (coalesced along n, 8 k's per thread) ----
    _Float16 breg[8];
#pragma unroll
    for (int i = 0; i < 8; ++i) breg[i] = B[(size_t)(k0 + bk + i) * N + bcol];

    __syncthreads();  // protect LDS from previous iteration's readers
    *(half8*)(As + arow * 32 + acol) = av;
    half8 bw;
#pragma unroll
    for (int i = 0; i < 8; ++i) bw[i] = breg[i];
    *(half8*)(Bs + bn * 32 + bk) = bw;
    __syncthreads();

    half8 af = *(const half8*)(As + (wave * 16 + l16) * 32 + quad * 8);
#pragma unroll
    for (int nt = 0; nt < 4; ++nt) {
      half8 bf = *(const half8*)(Bs + (nt * 16 + l16) * 32 + quad * 8);
      acc[nt] = MFMA16(af, bf, acc[nt]);
    }
  }

  const int rbase = wave * 16 + quad * 4;  // local row of acc[.][0]
  if (MODE == 0) {
    _Float16* C = (_Float16*)Cout;
#pragma unroll
    for (int nt = 0; nt < 4; ++nt) {
      int col = n0 + nt * 16 + l16;
#pragma unroll
      for (int r = 0; r < 4; ++r)
        C[(size_t)(m0 + rbase + r) * N + col] = (_Float16)acc[nt][r];
    }
  } else if (MODE == 1) {
    // scatter to vT[b][h][d][kv]; rows are kv (4 consecutive -> one 8B store)
    _Float16* C = (_Float16*)Cout;
    int b = m0 >> 10;
    int kvb = (m0 & 1023) + rbase;
#pragma unroll
    for (int nt = 0; nt < 4; ++nt) {
      int col = n0 + nt * 16 + l16;
      int h = col >> 6, d = col & 63;
      half4v pk;
#pragma unroll
      for (int r = 0; r < 4; ++r) pk[r] = (_Float16)acc[nt][r];
      *(half4v*)(C + (size_t)((b * NH + h) * DH + d) * SKV + kvb) = pk;
    }
  } else {
    float* C = (float*)Cout;
#pragma unroll
    for (int nt = 0; nt < 4; ++nt) {
      int col = n0 + nt * 16 + l16;
      float bb = bias[col];
#pragma unroll
      for (int r = 0; r < 4; ++r)
        C[(size_t)(m0 + rbase + r) * N + col] = acc[nt][r] + bb;
    }
  }
}

// ---------------------------------------------------------------- flash attention
// Q  [B*SQ, INNER] fp16 (head h at col h*64)
// Kp [B*SKV, INNER] fp16
// Vt [B, NH, DH, SKV] fp16
// O  [B*SQ, INNER] fp16
// Grid (SQ/64, B*NH), block 256. Wave w owns q-rows [16w,16w+16) of the 64-row tile.
__global__ __launch_bounds__(256) void flash_attn(const _Float16* __restrict__ Q,
                                                  const _Float16* __restrict__ Kp,
                                                  const _Float16* __restrict__ Vt,
                                                  _Float16* __restrict__ O) {
  __shared__ _Float16 plds[4][16 * 32];
  const int tid = threadIdx.x;
  const int wave = tid >> 6, lane = tid & 63;
  const int quad = lane >> 4, l16 = lane & 15;
  const int qblk = blockIdx.x, bh = blockIdx.y;
  const int b = bh >> 3, h = bh & 7;

  const size_t qrow0 = (size_t)b * SQ + qblk * 64 + wave * 16;
  const _Float16* qptr = Q + qrow0 * INNER + h * DH;
  const _Float16* kbase = Kp + (size_t)b * SKV * INNER + h * DH;
  const _Float16* vbase = Vt + (size_t)bh * DH * SKV;

  // Q A-fragments for d=0..31 and d=32..63 (kept in regs for the whole loop)
  half8 aq0 = *(const half8*)(qptr + (size_t)l16 * INNER + quad * 8);
  half8 aq1 = *(const half8*)(qptr + (size_t)l16 * INNER + 32 + quad * 8);

  floatx4 o[4] = {{0.f, 0.f, 0.f, 0.f}, {0.f, 0.f, 0.f, 0.f},
                  {0.f, 0.f, 0.f, 0.f}, {0.f, 0.f, 0.f, 0.f}};
  float mrow[4] = {-1e30f, -1e30f, -1e30f, -1e30f};
  float lrow[4] = {0.f, 0.f, 0.f, 0.f};
  const float scale = 0.125f;  // 64^-0.5

  for (int kv0 = 0; kv0 < SKV; kv0 += 32) {
    const _Float16* kp0 = kbase + (size_t)(kv0 + l16) * INNER + quad * 8;
    const _Float16* kp1 = kp0 + (size_t)16 * INNER;
    floatx4 s0 = {0.f, 0.f, 0.f, 0.f}, s1 = {0.f, 0.f, 0.f, 0.f};
    s0 = MFMA16(aq0, *(const half8*)kp0, s0);
    s0 = MFMA16(aq1, *(const half8*)(kp0 + 32), s0);
    s1 = MFMA16(aq0, *(const half8*)kp1, s1);
    s1 = MFMA16(aq1, *(const half8*)(kp1 + 32), s1);

#pragma unroll
    for (int r = 0; r < 4; ++r) {
      float a0 = s0[r] * scale;
      float a1 = s1[r] * scale;
      // row max over 32 kv (reduce across the 16-lane group)
      float t = fmaxf(a0, a1);
      t = fmaxf(t, __shfl_xor(t, 1));
      t = fmaxf(t, __shfl_xor(t, 2));
      t = fmaxf(t, __shfl_xor(t, 4));
      t = fmaxf(t, __shfl_xor(t, 8));
      float mnew = fmaxf(mrow[r], t);
      float alpha = __expf(mrow[r] - mnew);
      mrow[r] = mnew;
      float p0 = __expf(a0 - mnew);
      float p1 = __expf(a1 - mnew);
      float rs = p0 + p1;
      rs += __shfl_xor(rs, 1);
      rs += __shfl_xor(rs, 2);
      rs += __shfl_xor(rs, 4);
      rs += __shfl_xor(rs, 8);
      lrow[r] = lrow[r] * alpha + rs;
      o[0][r] *= alpha;
      o[1][r] *= alpha;
      o[2][r] *= alpha;
      o[3][r] *= alpha;
      // P: C-layout -> LDS (row-major [qrow][kv])
      plds[wave][(quad * 4 + r) * 32 + l16] = (_Float16)p0;
      plds[wave][(quad * 4 + r) * 32 + 16 + l16] = (_Float16)p1;
    }
    __syncthreads();
    // re-read P in A-operand layout
    half8 ap = *(const half8*)(plds[wave] + l16 * 32 + quad * 8);
    const _Float16* vp = vbase + kv0 + quad * 8;
#pragma unroll
    for (int nt = 0; nt < 4; ++nt) {
      half8 bv = *(const half8*)(vp + (size_t)(nt * 16 + l16) * SKV);
      o[nt] = MFMA16(ap, bv, o[nt]);
    }
    __syncthreads();
  }

  _Float16* op = O + qrow0 * INNER + h * DH;
  float inv[4];
#pragma unroll
  for (int r = 0; r < 4; ++r) inv[r] = 1.0f / lrow[r];
#pragma unroll
  for (int nt = 0; nt < 4; ++nt)
#pragma unroll
    for (int r = 0; r < 4; ++r)
      op[(size_t)(quad * 4 + r) * INNER + nt * 16 + l16] = (_Float16)(o[nt][r] * inv[r]);
}

// ---------------------------------------------------------------- launcher
extern "C" void kernel_launch(void* const* d_in, const int* in_sizes, int n_in,
                              void* d_out, int out_size, void* d_ws, size_t ws_size,
                              hipStream_t stream) {
  const float* x   = (const float*)d_in[0];
  const float* ctx = (const float*)d_in[1];
  const float* Wq  = (const float*)d_in[2];
  const float* Wk  = (const float*)d_in[3];
  const float* Wv  = (const float*)d_in[4];
  const float* Wo  = (const float*)d_in[5];
  const float* bo  = (const float*)d_in[6];
  float* out = (float*)d_out;

  _Float16* ws = (_Float16*)d_ws;
  _Float16* wqh = ws;                                  // 1024*512   = 524288
  _Float16* wkh = wqh + (size_t)QD * INNER;            // 768*512    = 393216
  _Float16* wvh = wkh + (size_t)CD * INNER;            // 768*512    = 393216
  _Float16* woh = wvh + (size_t)CD * INNER;            // 512*1024   = 524288
  _Float16* qh  = woh + (size_t)INNER * QD;            // 16384*512  = 8388608
  _Float16* kh  = qh + (size_t)BATCH * SQ * INNER;     // 4096*512   = 2097152
  _Float16* vth = kh + (size_t)BATCH * SKV * INNER;    // 4096*512   = 2097152
  _Float16* aoh = vth + (size_t)BATCH * SKV * INNER;   // 16384*512  = 8388608
  // total ws use: ~22.9M halfs = 45.8 MB

  // weight conversions (fp32 -> fp16)
  cvt_f32_f16<<<(QD * INNER / 4 + 255) / 256, 256, 0, stream>>>(Wq, wqh, QD * INNER / 4);
  cvt_f32_f16<<<(CD * INNER / 4 + 255) / 256, 256, 0, stream>>>(Wk, wkh, CD * INNER / 4);
  cvt_f32_f16<<<(CD * INNER / 4 + 255) / 256, 256, 0, stream>>>(Wv, wvh, CD * INNER / 4);
  cvt_f32_f16<<<(INNER * QD / 4 + 255) / 256, 256, 0, stream>>>(Wo, woh, INNER * QD / 4);

  // projections
  gemm16<0, 1><<<dim3(BATCH * SQ / 64, INNER / 64), 256, 0, stream>>>(
      (const void*)x, wqh, (void*)qh, nullptr, BATCH * SQ, INNER, QD);
  gemm16<0, 1><<<dim3(BATCH * SKV / 64, INNER / 64), 256, 0, stream>>>(
      (const void*)ctx, wkh, (void*)kh, nullptr, BATCH * SKV, INNER, CD);
  gemm16<1, 1><<<dim3(BATCH * SKV / 64, INNER / 64), 256, 0, stream>>>(
      (const void*)ctx, wvh, (void*)vth, nullptr, BATCH * SKV, INNER, CD);

  // attention
  flash_attn<<<dim3(SQ / 64, BATCH * NH), 256, 0, stream>>>(qh, kh, vth, aoh);

  // output projection + bias (fp32 out)
  gemm16<2, 0><<<dim3(BATCH * SQ / 64, QD / 64), 256, 0, stream>>>(
      (const void*)aoh, woh, (void*)out, bo, BATCH * SQ, QD, INNER);
}